// Round 14
// baseline (329.666 us; speedup 1.0000x reference)
//
#include <hip/hip_runtime.h>
#include <hip/hip_bf16.h>

typedef __attribute__((ext_vector_type(8))) short bf16x8;
typedef __attribute__((ext_vector_type(8))) unsigned short ushort8;
typedef __attribute__((ext_vector_type(4))) float f32x4;
typedef unsigned int u32;

#define D_DIM 512
#define C_DIM 1024
#define B_DIM 65536

__device__ __forceinline__ unsigned short f2bf(float x) {
  u32 u = __float_as_uint(x);
  u32 r = (u + 0x7fffu + ((u >> 16) & 1u)) >> 16;
  return (unsigned short)r;
}

__device__ __forceinline__ void async16(const void* g, void* l) {
  __builtin_amdgcn_global_load_lds(
      (const __attribute__((address_space(1))) u32*)g,
      (__attribute__((address_space(3))) u32*)l, 16, 0, 0);
}

// sharp(x) = sigmoid(10x-5) + sigmoid(-10x-5)
//          = (E t^2 + 2t + 1) / (E t^2 + (1+E) t + 1),  t = e^(10x-5), E = e^10.
__device__ __forceinline__ float sharpf(float x) {
  float t = __expf(10.f * x - 5.f);
  float u = 22026.4658f * t * t;
  float num = u + 2.f * t + 1.f;
  float den = u + 22027.4658f * t + 1.f;
  return num * __builtin_amdgcn_rcpf(den);
}

// Fused prep: blocks [0,16384) rownorm q; [16384,16640) rownorm k;
// [16640,17664) val transpose+cast. Branch is block-uniform.
__global__ __launch_bounds__(256) void prep_kernel(
    const float* __restrict__ q, const float* __restrict__ k,
    const float* __restrict__ val, unsigned short* __restrict__ qb,
    unsigned short* __restrict__ kb, unsigned short* __restrict__ vbT) {
  __shared__ float tile[32][33];
  int bid = blockIdx.x;
  if (bid < 16640) {
    const float* src = (bid < 16384) ? q : k;
    unsigned short* dst = (bid < 16384) ? qb : kb;
    int b = (bid < 16384) ? bid : bid - 16384;
    int row = b * 4 + (threadIdx.x >> 6);
    int lane = threadIdx.x & 63;
    const float* s = src + (size_t)row * D_DIM + lane * 8;
    float4 v0 = *(const float4*)s;
    float4 v1 = *(const float4*)(s + 4);
    float ss = v0.x * v0.x + v0.y * v0.y + v0.z * v0.z + v0.w * v0.w +
               v1.x * v1.x + v1.y * v1.y + v1.z * v1.z + v1.w * v1.w;
#pragma unroll
    for (int m = 32; m >= 1; m >>= 1) ss += __shfl_xor(ss, m);
    float rinv = rsqrtf(ss + 1e-12f);
    float tv[8] = {v0.x, v0.y, v0.z, v0.w, v1.x, v1.y, v1.z, v1.w};
    ushort8 o;
#pragma unroll
    for (int i = 0; i < 8; ++i) o[i] = f2bf(tv[i] * rinv);
    *(ushort8*)(dst + (size_t)row * D_DIM + lane * 8) = o;
  } else {
    int b = bid - 16640;
    int bx = b & 31;  // n tile
    int by = b >> 5;  // k tile
    int t = threadIdx.x;
    int r = t >> 5, c = t & 31;
#pragma unroll
    for (int i = 0; i < 4; ++i)
      tile[r + i * 8][c] = val[(size_t)(by * 32 + r + i * 8) * C_DIM + bx * 32 + c];
    __syncthreads();
#pragma unroll
    for (int i = 0; i < 4; ++i)
      vbT[(size_t)(bx * 32 + r + i * 8) * C_DIM + by * 32 + c] =
          f2bf(tile[c][r + i * 8]);
  }
}

// 256x256 GEMM, BK=64, 8 waves (2Mx4N), per-wave 128x64 (8mf x 4nf 16x16x32).
// m201-faithful 4-quadrant-phase schedule:
//  tile head: vmcnt(6) [=3 units in flight; all tile-T units retired]
//             (vmcnt(0) last tile); s_barrier (cross-wave DMA visibility).
//  ph0 (mh0,*nh0): read af[mh0](8) + bfr[nh0](4); stage UA-mh1(T+1);
//                  lgkm(0); 16 MFMA acc[0..3][0..1].
//  ph1 (mh0,nh1):  read bfr[nh1](4); stage UA-mh0(T+2); bar; lgkm(0);
//                  16 MFMA acc[0..3][2..3]; bar.
//  ph2 (mh1,nh0):  read af[mh1](8); stage UB-nh0(T+2); bar; lgkm(0);
//                  16 MFMA acc[4..7][0..1]; bar.
//  ph3 (mh1,nh1):  stage UB-nh1(T+2); bar; 16 MFMA acc[4..7][2..3].
// Write-after-read ledger: UA-mh1(T+1) lands in buf (T+1)&1 whose A-mh1 was
// last read in tile T-1 ph2 (retired before its close-bar). UA-mh0(T+2)/
// UB-nh0(T+2)/UB-nh1(T+2) land in buf T&1 regions whose readers retired
// before ph0/ph0/ph1 close-bars respectively; issue points are later. RAW:
// tile T's last unit UA-mh1(T) issued @T-1 ph0; 3 units (6 loads) follow ->
// vmcnt(6) at head retires it. sched_barrier(0) pins reads/MFMA around the
// raw s_barriers (C++ ds_reads are compiler-mobile otherwise).
// Units (2 x async16/thread): UA-mh = A rows {mh*64..+63}u{128+mh*64..+63};
// UB-nh = B rows wc-grp*64 + nh*32 + [0,32). Each wave-load = 8 contiguous
// rows (linear dest; inverse-swizzled global source col, XOR (r&7)<<3).
// SHARP epilogue: sharp -> swizzled LDS scatter -> coalesced 16B w store ->
// wc-reduce rowsums -> rsum_part[n][row]. !SHARP: rinv = rcp(sum of 4
// partials) inline, f32 store.
template <int K, bool SHARP>
__global__ __launch_bounds__(512, 2) void gemm256_kernel(
    const unsigned short* __restrict__ A, const unsigned short* __restrict__ Bm,
    unsigned short* __restrict__ wout, float* __restrict__ rsum,
    float* __restrict__ fout) {
  __shared__ unsigned short smem[65536];  // 128 KB
  const int NKT = K / 64;
  const int bid = blockIdx.x;
  // XCD-chunked bijective swizzle: nwg=1024, 8 XCDs, 128 per chunk.
  const int wg = (bid & 7) * 128 + (bid >> 3);
  const int m0 = (wg >> 2) * 256;
  const int n0 = (wg & 3) * 256;
  const int t = threadIdx.x;
  const int lane = t & 63;
  const int wv = t >> 6;
  const int wr = wv >> 2;
  const int wc = wv & 3;
  const int lo = lane & 15, hi = lane >> 4;
  const int swu = (lo & 7) << 3;

  auto stageA = [&](int T, int mh) {
    const int d2 = (T & 1) * 32768;
#pragma unroll
    for (int i = 0; i < 2; ++i) {
      int s = i * 512 + t;  // 0..1023
      int rb = s >> 3, slot = s & 7;
      int r = mh * 64 + (rb & 63) + (rb >> 6) * 128;
      int c = slot * 8;
      int cl = c ^ ((r & 7) << 3);
      async16(A + (size_t)(m0 + r) * K + (size_t)T * 64 + cl,
              &smem[d2 + r * 64 + c]);
    }
  };
  auto stageB = [&](int T, int nh) {
    const int d2 = (T & 1) * 32768;
#pragma unroll
    for (int i = 0; i < 2; ++i) {
      int s = i * 512 + t;
      int rb = s >> 3, slot = s & 7;
      int r = (rb >> 5) * 64 + nh * 32 + (rb & 31);
      int c = slot * 8;
      int cl = c ^ ((r & 7) << 3);
      async16(Bm + (size_t)(n0 + r) * K + (size_t)T * 64 + cl,
              &smem[d2 + 16384 + r * 64 + c]);
    }
  };

  f32x4 acc[8][4];
#pragma unroll
  for (int i = 0; i < 8; ++i)
#pragma unroll
    for (int j = 0; j < 4; ++j) acc[i][j] = (f32x4){0.f, 0.f, 0.f, 0.f};

  // prologue: steady-state issue order (oldest->newest):
  stageA(0, 0); stageB(0, 0); stageB(0, 1); stageA(0, 1);
  stageA(1, 0); stageB(1, 0); stageB(1, 1);  // 7 units = 14 loads

  bf16x8 af[4][2], bfr[4][2];

#pragma unroll 1
  for (int T = 0; T < NKT; ++T) {
    if (T == NKT - 1) {
      asm volatile("s_waitcnt vmcnt(0)" ::: "memory");
    } else {
      asm volatile("s_waitcnt vmcnt(6)" ::: "memory");
    }
    __builtin_amdgcn_s_barrier();
    __builtin_amdgcn_sched_barrier(0);
    const int d = (T & 1) * 32768;
    // ---- ph0: af[mh0] + bfr[nh0]; stage UA-mh1(T+1)
#pragma unroll
    for (int mf = 0; mf < 4; ++mf)
#pragma unroll
      for (int ks = 0; ks < 2; ++ks) {
        int r = wr * 128 + mf * 16 + lo;
        af[mf][ks] = *(const bf16x8*)&smem[d + r * 64 + ((ks * 32 + hi * 8) ^ swu)];
      }
#pragma unroll
    for (int nf = 0; nf < 2; ++nf)
#pragma unroll
      for (int ks = 0; ks < 2; ++ks) {
        int r = wc * 64 + nf * 16 + lo;
        bfr[nf][ks] =
            *(const bf16x8*)&smem[d + 16384 + r * 64 + ((ks * 32 + hi * 8) ^ swu)];
      }
    if (T + 1 < NKT) stageA(T + 1, 1);
    asm volatile("s_waitcnt lgkmcnt(0)" ::: "memory");
    __builtin_amdgcn_sched_barrier(0);
    __builtin_amdgcn_s_setprio(1);
#pragma unroll
    for (int mf = 0; mf < 4; ++mf)
#pragma unroll
      for (int nf = 0; nf < 2; ++nf)
#pragma unroll
        for (int ks = 0; ks < 2; ++ks)
          acc[mf][nf] = __builtin_amdgcn_mfma_f32_16x16x32_bf16(
              af[mf][ks], bfr[nf][ks], acc[mf][nf], 0, 0, 0);
    __builtin_amdgcn_s_setprio(0);
    __builtin_amdgcn_sched_barrier(0);
    __builtin_amdgcn_s_barrier();  // ph0 close
    // ---- ph1: bfr[nh1]; stage UA-mh0(T+2)
#pragma unroll
    for (int nf = 2; nf < 4; ++nf)
#pragma unroll
      for (int ks = 0; ks < 2; ++ks) {
        int r = wc * 64 + nf * 16 + lo;
        bfr[nf][ks] =
            *(const bf16x8*)&smem[d + 16384 + r * 64 + ((ks * 32 + hi * 8) ^ swu)];
      }
    if (T + 2 < NKT) stageA(T + 2, 0);
    __builtin_amdgcn_sched_barrier(0);
    __builtin_amdgcn_s_barrier();  // ph1 open
    asm volatile("s_waitcnt lgkmcnt(0)" ::: "memory");
    __builtin_amdgcn_sched_barrier(0);
    __builtin_amdgcn_s_setprio(1);
#pragma unroll
    for (int mf = 0; mf < 4; ++mf)
#pragma unroll
      for (int nf = 2; nf < 4; ++nf)
#pragma unroll
        for (int ks = 0; ks < 2; ++ks)
          acc[mf][nf] = __builtin_amdgcn_mfma_f32_16x16x32_bf16(
              af[mf][ks], bfr[nf][ks], acc[mf][nf], 0, 0, 0);
    __builtin_amdgcn_s_setprio(0);
    __builtin_amdgcn_sched_barrier(0);
    __builtin_amdgcn_s_barrier();  // ph1 close
    // ---- ph2: af[mh1]; stage UB-nh0(T+2)
#pragma unroll
    for (int mf = 0; mf < 4; ++mf)
#pragma unroll
      for (int ks = 0; ks < 2; ++ks) {
        int r = wr * 128 + 64 + mf * 16 + lo;
        af[mf][ks] = *(const bf16x8*)&smem[d + r * 64 + ((ks * 32 + hi * 8) ^ swu)];
      }
    if (T + 2 < NKT) stageB(T + 2, 0);
    __builtin_amdgcn_sched_barrier(0);
    __builtin_amdgcn_s_barrier();  // ph2 open
    asm volatile("s_waitcnt lgkmcnt(0)" ::: "memory");
    __builtin_amdgcn_sched_barrier(0);
    __builtin_amdgcn_s_setprio(1);
#pragma unroll
    for (int mf = 0; mf < 4; ++mf)
#pragma unroll
      for (int nf = 0; nf < 2; ++nf)
#pragma unroll
        for (int ks = 0; ks < 2; ++ks)
          acc[4 + mf][nf] = __builtin_amdgcn_mfma_f32_16x16x32_bf16(
              af[mf][ks], bfr[nf][ks], acc[4 + mf][nf], 0, 0, 0);
    __builtin_amdgcn_s_setprio(0);
    __builtin_amdgcn_sched_barrier(0);
    __builtin_amdgcn_s_barrier();  // ph2 close
    // ---- ph3: no reads; stage UB-nh1(T+2)
    if (T + 2 < NKT) stageB(T + 2, 1);
    __builtin_amdgcn_sched_barrier(0);
    __builtin_amdgcn_s_barrier();  // ph3 open
    __builtin_amdgcn_s_setprio(1);
#pragma unroll
    for (int mf = 0; mf < 4; ++mf)
#pragma unroll
      for (int nf = 2; nf < 4; ++nf)
#pragma unroll
        for (int ks = 0; ks < 2; ++ks)
          acc[4 + mf][nf] = __builtin_amdgcn_mfma_f32_16x16x32_bf16(
              af[mf][ks], bfr[nf][ks], acc[4 + mf][nf], 0, 0, 0);
    __builtin_amdgcn_s_setprio(0);
    __builtin_amdgcn_sched_barrier(0);
    // no ph3 close barrier: next tile's head barrier serves
  }
  __syncthreads();  // K-loop drained (vmcnt 0 at last head); reuse LDS

  if (SHARP) {
    float rs[8][4];
#pragma unroll
    for (int i = 0; i < 8; ++i)
#pragma unroll
      for (int j = 0; j < 4; ++j) rs[i][j] = 0.f;
    unsigned short* ep = smem;  // 256x256 u16 = 128 KB
#pragma unroll
    for (int mf = 0; mf < 8; ++mf)
#pragma unroll
      for (int nf = 0; nf < 4; ++nf)
#pragma unroll
        for (int j = 0; j < 4; ++j) {
          float s = sharpf(acc[mf][nf][j]);
          rs[mf][j] += s;
          int rl = wr * 128 + mf * 16 + (hi << 2) + j;
          int cl = (wc * 64 + nf * 16 + lo) ^ (((rl >> 2) & 3) << 4);
          ep[rl * 256 + cl] = f2bf(s);
        }
#pragma unroll
    for (int mf = 0; mf < 8; ++mf)
#pragma unroll
      for (int j = 0; j < 4; ++j) {
        float v = rs[mf][j];
        v += __shfl_xor(v, 1);
        v += __shfl_xor(v, 2);
        v += __shfl_xor(v, 4);
        v += __shfl_xor(v, 8);
        rs[mf][j] = v;
      }
    __syncthreads();
#pragma unroll
    for (int pass = 0; pass < 16; ++pass) {
      int idx = pass * 4096 + t * 8;
      int row = idx >> 8, col = idx & 255;
      int phys = row * 256 + (col ^ (((row >> 2) & 3) << 4));
      *(ushort8*)&wout[(size_t)(m0 + row) * C_DIM + n0 + col] =
          *(const ushort8*)&ep[phys];
    }
    __syncthreads();
    float* rbuf = (float*)smem;  // [4][256]
    if (lo == 0) {
#pragma unroll
      for (int mf = 0; mf < 8; ++mf)
#pragma unroll
        for (int j = 0; j < 4; ++j)
          rbuf[wc * 256 + wr * 128 + mf * 16 + (hi << 2) + j] = rs[mf][j];
    }
    __syncthreads();
    if (t < 256) {
      float v = (rbuf[t] + rbuf[256 + t]) + (rbuf[512 + t] + rbuf[768 + t]);
      rsum[(size_t)(wg & 3) * B_DIM + m0 + t] = v;  // rsum = rsum_part here
    }
  } else {
    // rinv from the 4 rowsum partials (L2-hot, replaces reduce kernel)
    float rinv[8][4];
#pragma unroll
    for (int mf = 0; mf < 8; ++mf) {
      int base = m0 + wr * 128 + mf * 16 + (hi << 2);
      float4 p0 = *(const float4*)&rsum[base];
      float4 p1 = *(const float4*)&rsum[B_DIM + base];
      float4 p2 = *(const float4*)&rsum[2 * B_DIM + base];
      float4 p3 = *(const float4*)&rsum[3 * B_DIM + base];
      rinv[mf][0] = __builtin_amdgcn_rcpf((p0.x + p1.x) + (p2.x + p3.x));
      rinv[mf][1] = __builtin_amdgcn_rcpf((p0.y + p1.y) + (p2.y + p3.y));
      rinv[mf][2] = __builtin_amdgcn_rcpf((p0.z + p1.z) + (p2.z + p3.z));
      rinv[mf][3] = __builtin_amdgcn_rcpf((p0.w + p1.w) + (p2.w + p3.w));
    }
#pragma unroll
    for (int mf = 0; mf < 8; ++mf)
#pragma unroll
      for (int nf = 0; nf < 4; ++nf)
#pragma unroll
        for (int j = 0; j < 4; ++j)
          fout[(size_t)(m0 + wr * 128 + mf * 16 + (hi << 2) + j) * C_DIM +
               n0 + wc * 64 + nf * 16 + lo] = acc[mf][nf][j] * rinv[mf][j];
  }
}

extern "C" void kernel_launch(void* const* d_in, const int* in_sizes, int n_in,
                              void* d_out, int out_size, void* d_ws, size_t ws_size,
                              hipStream_t stream) {
  const float* query = (const float*)d_in[0];
  const float* key = (const float*)d_in[1];
  const float* val = (const float*)d_in[2];
  float* out = (float*)d_out;
  const int B = in_sizes[0] / D_DIM;  // 65536

  char* ws = (char*)d_ws;
  unsigned short* kb = (unsigned short*)(ws);                         // 1 MB
  unsigned short* vbT = (unsigned short*)(ws + (1ull << 20));         // 2 MB
  float* rsum_part = (float*)(ws + 3ull * (1ull << 20));              // 1 MB
  unsigned short* qb = (unsigned short*)(ws + 4ull * (1ull << 20));   // 64 MB
  unsigned short* wbf = (unsigned short*)(ws + 68ull * (1ull << 20)); // 128 MB

  prep_kernel<<<dim3(17664), dim3(256), 0, stream>>>(query, key, val, qb, kb, vbT);

  dim3 grid((B / 256) * (C_DIM / 256));  // 1024 blocks
  gemm256_kernel<D_DIM, true><<<grid, dim3(512), 0, stream>>>(qb, kb, wbf, rsum_part, nullptr);
  gemm256_kernel<C_DIM, false><<<grid, dim3(512), 0, stream>>>(wbf, vbT, nullptr, rsum_part, out);
}